// Round 4
// baseline (505.989 us; speedup 1.0000x reference)
//
#include <hip/hip_runtime.h>
#include <cstdint>
#include <cstddef>

// total = sum(DW*Z) + 2e-4*sum(1-(2Th-1)^2) + 0.2*sum_i t_i^2
// DW = W - s*(Q+Th), Z[i,j] = sum_k DW[i,k]*Sigma[j,k], t_i = sum_j W[i,j]*Z[i,j]
//
// R4 megakernel: one block per 64 output rows. DW tile lives ONLY in LDS
// (full K=1024 resident, 128KB, XOR-swizzled chunks). Sigma bf16 streamed
// from L2 through a 20KB pitch-80 stage buffer (4 n-passes x 32 k-stages),
// register-prefetched one stage ahead (T14). Epilogue reads DW from LDS and
// W from L2; per-block t_i is complete -> 0.2*t^2 + act + 2e-4*bsum fold into
// atomicAdds on out. Kills DW 128MB round-trip + 2 launches + finish pass.
// R5: identical resubmit — R4 bench died with "container failed twice"
// (infra), kernel audited clean (bounds/LDS/barriers).

#define DOUT 32768
#define DIN  1024

typedef __bf16 bf16x8 __attribute__((ext_vector_type(8)));
typedef float  f32x4  __attribute__((ext_vector_type(4)));
typedef unsigned short u16x8 __attribute__((ext_vector_type(8)));
typedef unsigned short u16x4 __attribute__((ext_vector_type(4)));

__device__ __forceinline__ unsigned short f2bf(float f) {
  union { float f; unsigned u; } v; v.f = f;
  unsigned u = v.u + 0x7fffu + ((v.u >> 16) & 1u);   // RNE
  return (unsigned short)(u >> 16);
}
__device__ __forceinline__ float bf2f(unsigned short b) {
  union { float f; unsigned u; } v; v.u = ((unsigned)b) << 16;
  return v.f;
}

// ---------------- Sigma fp32 -> bf16 (2MB, L2-resident for mega) ----------------
__global__ __launch_bounds__(256) void sconv(const f32x4* __restrict__ S4,
                                             u16x4* __restrict__ O4)
{
  const int idx = blockIdx.x * 256 + threadIdx.x;
  f32x4 v = S4[idx];
  u16x4 o;
  o[0] = f2bf(v[0]); o[1] = f2bf(v[1]); o[2] = f2bf(v[2]); o[3] = f2bf(v[3]);
  O4[idx] = o;
}

// closed-form squashed tanh: clamp(1.1 - 1.2/(e^{2x}+1), 0, 1)
#define TH(x) ({ float e_ = __builtin_amdgcn_exp2f((x) * 2.885390082f); \
                 float th_ = 1.1f - 1.2f * __builtin_amdgcn_rcpf(e_ + 1.f); \
                 fminf(fmaxf(th_, 0.f), 1.f); })

__global__ __launch_bounds__(512, 1) void mega(
    const float* __restrict__ Wf, const float* __restrict__ Qf,
    const float* __restrict__ Tf, const float* __restrict__ sv,
    const unsigned short* __restrict__ SG,   // [DIN][DIN] bf16 bits
    float* __restrict__ out)
{
  // As: 16 k-tiles of [64 rows][8 chunks x 8 bf16]; logical chunk c of row r
  // stored at physical chunk c^(r&7)  (same swizzle as the verified R2 gemm).
  __shared__ alignas(16) unsigned short As[16 * 4096];   // 131072 B
  // Bs: 256 n-rows x 32 k bf16, row pitch 80B (5x16B): the 16-lane frag read
  // (rows stride 80B, fixed 16B slot) lands 2-way on banks = free.
  __shared__ alignas(16) unsigned char Bs[256 * 80];     // 20480 B
  __shared__ float tred[64][8];                          // 2048 B

  const int tid  = threadIdx.x;
  const int m0   = blockIdx.x * 64;
  const int lane = tid & 63;
  const int w    = tid >> 6;        // 0..7 waves
  const int q    = lane >> 4;       // 0..3
  const int mr   = lane & 15;
  const int mr7  = mr & 7;

  // ---- Phase A: DW = W - s*(Q+Th) -> As (bf16); bsum partial ----
  float bsum = 0.f;
  {
    const int r  = tid >> 3;                    // 0..63 (8 thr/row)
    const int c0 = tid & 7;                     // chunk-in-ktile this thread owns
    const float s_r = sv[m0 + r];
    const size_t rowb = (size_t)(m0 + r) * DIN + c0 * 8;
    const int abase = r * 64 + ((c0 ^ (r & 7)) << 3);
#pragma unroll 1
    for (int j = 0; j < 16; j += 2) {           // 2 k-tiles per iter (MLP batch)
      const float* p  = Wf + rowb + (size_t)j * 64;
      const float* pq = Qf + rowb + (size_t)j * 64;
      const float* pt = Tf + rowb + (size_t)j * 64;
      f32x4 wva0 = *(const f32x4*)(p);      f32x4 wva1 = *(const f32x4*)(p + 4);
      f32x4 wva2 = *(const f32x4*)(p + 64); f32x4 wva3 = *(const f32x4*)(p + 68);
      f32x4 qva0 = __builtin_nontemporal_load((const f32x4*)(pq));
      f32x4 qva1 = __builtin_nontemporal_load((const f32x4*)(pq + 4));
      f32x4 qva2 = __builtin_nontemporal_load((const f32x4*)(pq + 64));
      f32x4 qva3 = __builtin_nontemporal_load((const f32x4*)(pq + 68));
      f32x4 tva0 = __builtin_nontemporal_load((const f32x4*)(pt));
      f32x4 tva1 = __builtin_nontemporal_load((const f32x4*)(pt + 4));
      f32x4 tva2 = __builtin_nontemporal_load((const f32x4*)(pt + 64));
      f32x4 tva3 = __builtin_nontemporal_load((const f32x4*)(pt + 68));
      u16x8 d0, d1;
#pragma unroll
      for (int e = 0; e < 4; ++e) {
        float t0 = TH(tva0[e]); float u0 = 2.f * t0 - 1.f; bsum += 1.f - u0 * u0;
        d0[e]     = f2bf(wva0[e] - s_r * (qva0[e] + t0));
        float t1 = TH(tva1[e]); float u1 = 2.f * t1 - 1.f; bsum += 1.f - u1 * u1;
        d0[e + 4] = f2bf(wva1[e] - s_r * (qva1[e] + t1));
        float t2 = TH(tva2[e]); float u2 = 2.f * t2 - 1.f; bsum += 1.f - u2 * u2;
        d1[e]     = f2bf(wva2[e] - s_r * (qva2[e] + t2));
        float t3 = TH(tva3[e]); float u3 = 2.f * t3 - 1.f; bsum += 1.f - u3 * u3;
        d1[e + 4] = f2bf(wva3[e] - s_r * (qva3[e] + t3));
      }
      *(u16x8*)&As[(j)     * 4096 + abase] = d0;
      *(u16x8*)&As[(j + 1) * 4096 + abase] = d1;
    }
  }

  // ---- Main: 4 n-passes (256 cols) x 32 k-stages (32 k each) ----
  const int pnrow = tid >> 1;                 // 0..255: Bs row this thread stages
  const int pkc   = (tid & 1) * 2;            // chunk pair (2x16B contiguous)
  u16x8 pr0, pr1;
#define PF(np_, kst_) { \
    const unsigned short* gp_ = SG + (size_t)((np_) * 256 + pnrow) * DIN + (kst_) * 32 + pkc * 8; \
    pr0 = *(const u16x8*)gp_; pr1 = *(const u16x8*)(gp_ + 8); }

  f32x4 acc[4][2];
#pragma unroll
  for (int ti = 0; ti < 4; ++ti) { acc[ti][0] = (f32x4){0,0,0,0}; acc[ti][1] = (f32x4){0,0,0,0}; }
  float ts[4][4];
#pragma unroll
  for (int ti = 0; ti < 4; ++ti)
#pragma unroll
    for (int rr = 0; rr < 4; ++rr) ts[ti][rr] = 0.f;
  float actp = 0.f;

  PF(0, 0);
#pragma unroll 1
  for (int st = 0; st < 128; ++st) {
    const int np  = st >> 5;
    const int kst = st & 31;
    __syncthreads();                           // prev MFMA done reading Bs (st=0: As visible)
    *(u16x8*)&Bs[pnrow * 80 + pkc * 16]      = pr0;
    *(u16x8*)&Bs[pnrow * 80 + pkc * 16 + 16] = pr1;
    if (st < 127) { const int s1 = st + 1; PF(s1 >> 5, s1 & 31); }
    __syncthreads();                           // Bs visible
    {
      const int CG   = kst * 4 + q;            // global k-chunk 0..127
      const int aoff = (CG >> 3) * 4096 + (((CG & 7) ^ mr7) << 3) + mr * 64;
      bf16x8 a0 = *(const bf16x8*)&As[aoff];
      bf16x8 a1 = *(const bf16x8*)&As[aoff + 16 * 64];
      bf16x8 a2 = *(const bf16x8*)&As[aoff + 32 * 64];
      bf16x8 a3 = *(const bf16x8*)&As[aoff + 48 * 64];
      const int boff = (w * 32 + mr) * 80 + q * 16;
      bf16x8 b0 = *(const bf16x8*)&Bs[boff];
      bf16x8 b1 = *(const bf16x8*)&Bs[boff + 16 * 80];
      acc[0][0] = __builtin_amdgcn_mfma_f32_16x16x32_bf16(a0, b0, acc[0][0], 0, 0, 0);
      acc[0][1] = __builtin_amdgcn_mfma_f32_16x16x32_bf16(a0, b1, acc[0][1], 0, 0, 0);
      acc[1][0] = __builtin_amdgcn_mfma_f32_16x16x32_bf16(a1, b0, acc[1][0], 0, 0, 0);
      acc[1][1] = __builtin_amdgcn_mfma_f32_16x16x32_bf16(a1, b1, acc[1][1], 0, 0, 0);
      acc[2][0] = __builtin_amdgcn_mfma_f32_16x16x32_bf16(a2, b0, acc[2][0], 0, 0, 0);
      acc[2][1] = __builtin_amdgcn_mfma_f32_16x16x32_bf16(a2, b1, acc[2][1], 0, 0, 0);
      acc[3][0] = __builtin_amdgcn_mfma_f32_16x16x32_bf16(a3, b0, acc[3][0], 0, 0, 0);
      acc[3][1] = __builtin_amdgcn_mfma_f32_16x16x32_bf16(a3, b1, acc[3][1], 0, 0, 0);
    }
    if (kst == 31) {
      // epilogue for n-pass np: C/D layout col=lane&15, row=q*4+rr
#pragma unroll
      for (int ti = 0; ti < 4; ++ti) {
#pragma unroll
        for (int rr = 0; rr < 4; ++rr) {
          const int il  = ti * 16 + q * 4 + rr;
          const int il7 = (q * 4 + rr) & 7;
          const float* wrow = Wf + (size_t)(m0 + il) * DIN;
#pragma unroll
          for (int tj = 0; tj < 2; ++tj) {
            const int jj = np * 256 + w * 32 + tj * 16 + mr;
            const float z = acc[ti][tj][rr];
            ts[ti][rr] = fmaf(wrow[jj], z, ts[ti][rr]);
            const int del = (jj >> 6) * 4096 + il * 64 + ((((jj >> 3) & 7) ^ il7) << 3) + (jj & 7);
            actp = fmaf(bf2f(As[del]), z, actp);
          }
        }
      }
#pragma unroll
      for (int ti = 0; ti < 4; ++ti) { acc[ti][0] = (f32x4){0,0,0,0}; acc[ti][1] = (f32x4){0,0,0,0}; }
    }
  }

  // ---- Reductions ----
  float cpart = actp + 2.0e-4f * bsum;
  for (int off = 32; off; off >>= 1) cpart += __shfl_down(cpart, off);
  if (lane == 0) atomicAdd(out, cpart);

#pragma unroll
  for (int ti = 0; ti < 4; ++ti)
#pragma unroll
    for (int rr = 0; rr < 4; ++rr) {
      float v = ts[ti][rr];
      v += __shfl_xor(v, 8, 16); v += __shfl_xor(v, 4, 16);
      v += __shfl_xor(v, 2, 16); v += __shfl_xor(v, 1, 16);
      if (mr == 0) tred[ti * 16 + q * 4 + rr][w] = v;
    }
  __syncthreads();
  if (tid < 64) {
    float t = 0.f;
#pragma unroll
    for (int k = 0; k < 8; ++k) t += tred[tid][k];
    float g = 0.2f * t * t;                    // lamb*4 = 0.05*4
    for (int off = 32; off; off >>= 1) g += __shfl_down(g, off);
    if (tid == 0) atomicAdd(out, g);
  }
}

extern "C" void kernel_launch(void* const* d_in, const int* in_sizes, int n_in,
                              void* d_out, int out_size, void* d_ws, size_t ws_size,
                              hipStream_t stream) {
  const float* W     = (const float*)d_in[0];
  const float* Sigma = (const float*)d_in[1];
  const float* Q     = (const float*)d_in[2];
  const float* s     = (const float*)d_in[3];
  const float* Theta = (const float*)d_in[4];
  float* out = (float*)d_out;

  unsigned short* SigB = (unsigned short*)d_ws;   // 2MB Sigma bf16

  (void)hipMemsetAsync(d_out, 0, 4, stream);      // out accumulated via atomics

  sconv<<<(DIN * DIN) / 1024, 256, 0, stream>>>((const f32x4*)Sigma, (u16x4*)SigB);
  mega<<<DOUT / 64, 512, 0, stream>>>(W, Q, Theta, s, SigB, out);
}